// Round 8
// baseline (306.631 us; speedup 1.0000x reference)
//
#include <hip/hip_runtime.h>
#include <hip/hip_bf16.h>

#define HID 128

typedef __attribute__((ext_vector_type(8))) short short8;   // 8 x bf16 (4 VGPRs)
typedef __attribute__((ext_vector_type(4))) float f32x4;    // MFMA C/D

static __device__ __forceinline__ short f2bf(float x) {
    __hip_bfloat16 h = __float2bfloat16(x);   // RNE
    return *reinterpret_cast<short*>(&h);
}

// ---------------------------------------------------------------------------
// K1: the two INDEPENDENT 128x128 products in one launch, plus the bias
// chain parallelized over its 128 outputs.
//   blocks 0..127   : P_left  = Wo  @ W_mo      (row b)
//   blocks 128..255 : P_right = Wiv @ Wv        (row b-128)
//   block  256      : cv = 0.5*(Wo@(W_mo@(Wiv@bv + biv) + b_mo) + bo)
// ---------------------------------------------------------------------------
__global__ void prep_products(const float* __restrict__ Wo,
                              const float* __restrict__ W_mo,
                              const float* __restrict__ Wiv,
                              const float* __restrict__ Wv,
                              const float* __restrict__ bv,
                              const float* __restrict__ biv,
                              const float* __restrict__ b_mo,
                              const float* __restrict__ bo,
                              float* __restrict__ Pl,
                              float* __restrict__ Pr,
                              float* __restrict__ cv)
{
    const int j = threadIdx.x;
    const int b = blockIdx.x;
    __shared__ float sh[HID];

    if (b < 256) {
        const float* A = (b < 128) ? Wo   : Wiv;
        const float* B = (b < 128) ? W_mo : Wv;
        float*       C = (b < 128) ? Pl   : Pr;
        const int i = b & 127;
        sh[j] = A[i * HID + j];
        __syncthreads();
        float s = 0.f;
        #pragma unroll 16
        for (int k = 0; k < HID; ++k) s += sh[k] * B[k * HID + j];
        C[i * HID + j] = s;
    } else {
        // bias chain: 3 matvecs, each parallel over the 128 outputs.
        sh[j] = bv[j];
        __syncthreads();
        float t = biv[j];
        #pragma unroll 16
        for (int k = 0; k < HID; ++k) t += Wiv[j * HID + k] * sh[k];
        __syncthreads(); sh[j] = t; __syncthreads();
        t = b_mo[j];
        #pragma unroll 16
        for (int k = 0; k < HID; ++k) t += W_mo[j * HID + k] * sh[k];
        __syncthreads(); sh[j] = t; __syncthreads();
        t = bo[j];
        #pragma unroll 16
        for (int k = 0; k < HID; ++k) t += Wo[j * HID + k] * sh[k];
        cv[j] = 0.5f * t;
    }
}

// ---------------------------------------------------------------------------
// K2: M' = bf16( I + 0.5 * P_left @ P_right )   (row-major [n][k])
// ---------------------------------------------------------------------------
__global__ void prep_final(const float* __restrict__ Pl,
                           const float* __restrict__ Pr,
                           __hip_bfloat16* __restrict__ Mb)
{
    const int i = blockIdx.x, j = threadIdx.x;
    __shared__ float sh[HID];
    sh[j] = Pl[i * HID + j];
    __syncthreads();
    float s = 0.f;
    #pragma unroll 16
    for (int k = 0; k < HID; ++k) s += sh[k] * Pr[k * HID + j];
    Mb[i * HID + j] = __float2bfloat16(((i == j) ? 1.0f : 0.0f) + 0.5f * s);
}

// ---------------------------------------------------------------------------
// Main: out[e][:] = ea[e][:] @ M'^T + cv      (fp32 in/out, bf16 MFMA)
//
// R8 analysis: delivery rate pinned at ~2.7 B/cy/CU per stream across ALL
// prior structures (register scatter, 2x occupancy, LDS-DMA depth 2/3,
// wave-private no-barrier, dense reg loads + LDS transpose) while an
// m13-style streaming copy sustains 5.1+5.1 B/cy/CU with the SAME 1:1
// read:write mix. R6 showed 8KB stages with >=64KB/CU in flight still take
// ~24K cy -> not a latency bound, a delivery-RATE cap. The one structural
// axis never varied: every variant issues loads in per-block BURSTS gated
// by a loop-carried dependency (barrier chain or vmcnt gate), then goes
// quiet; m13 has no loop at all.
//
// Decisive A/B: REMOVE THE LOOP. One tile per block, grid = numTiles
// (E = 250000 = 15625 x 16 exactly). Each block: dense coalesced loads
// (2 dwordx4/thread) -> swizzled ds_write -> __syncthreads -> fragment
// ds_read -> 8 MFMA/wave -> contiguous stores -> EXIT. Pipelining via
// block churn: ~6 resident blocks/CU are always at different phases, so
// load issue is continuous by construction. If this doesn't move, the
// ~5 B/cy/CU mixed-stream cap is structure-independent = the roofline.
// ---------------------------------------------------------------------------
__global__ __launch_bounds__(256) void edge_gemm(
    const float* __restrict__ ea,
    const __hip_bfloat16* __restrict__ Mb,   // [128][128] bf16: M'[n][k]
    const float* __restrict__ cvec,          // [128] = 0.5*c
    float* __restrict__ out,
    int E, int numTiles)
{
    __shared__ __align__(16) float lds[2048];   // one 16-row x 512 B tile

    const int t = blockIdx.x;
    if (t >= numTiles) return;

    const int lane  = threadIdx.x & 63;
    const int wv    = threadIdx.x >> 6;
    const int q     = lane >> 4;      // 0..3
    const int c     = lane & 15;      // 0..15
    const int ncol0 = wv * 32;        // this wave's 32 output cols

    // Dense-load addressing: thread tid covers tile bytes [tid*32, +32) =
    // row tid>>4, row-bytes (tid&15)*32 .. +32.  Perfectly coalesced.
    const int ldrow = threadIdx.x >> 4;         // 0..15
    const int ldoff = (threadIdx.x & 15) * 32;  // 32B-aligned byte in row

    // Issue the tile loads FIRST so they are in flight under everything else.
    float4 r0, r1;
    {
        int row = t * 16 + ldrow; if (row > E - 1) row = E - 1;
        const char* p = (const char*)ea + (size_t)row * 512 + ldoff;
        r0 = *reinterpret_cast<const float4*>(p);
        r1 = *reinterpret_cast<const float4*>(p + 16);
    }

    // A-frag (L2-hot): lane (q,c) holds M'[ncol0 + nt*16 + c][kk*32 + q*8 ..]
    short8 Mfrag[2][4];
    #pragma unroll
    for (int nt = 0; nt < 2; ++nt) {
        const __hip_bfloat16* mp = Mb + (size_t)(ncol0 + nt * 16 + c) * HID + q * 8;
        #pragma unroll
        for (int kk = 0; kk < 4; ++kk)
            Mfrag[nt][kk] = *reinterpret_cast<const short8*>(mp + kk * 32);
    }
    f32x4 cvp[2];
    #pragma unroll
    for (int nt = 0; nt < 2; ++nt)
        cvp[nt] = *reinterpret_cast<const f32x4*>(cvec + ncol0 + nt * 16 + q * 4);

    // ds_write: global (r, b) lands at LDS byte r*512 + (b ^ ((r&7)<<4)).
    const int wsw  = (ldrow & 7) << 4;
    const int wad0 = ldrow * 512 + (ldoff ^ wsw);
    const int wad1 = wad0 ^ 16;
    {
        char* lb = (char*)lds;
        *reinterpret_cast<float4*>(lb + wad0) = r0;
        *reinterpret_cast<float4*>(lb + wad1) = r1;
    }
    __syncthreads();

    // ds_read fragment addressing (proven R3/R5/R6/R7):
    // ea[row c][byte kk*128 + q*32 + h*16] at LDS byte
    // c*512 + ((kk*128 + q*32 + h*16) ^ ((c&7)<<4)); XOR fields disjoint.
    const int swz   = (c & 7) << 4;
    const int rbase = c * 512 + ((q * 32) ^ (swz & 0x60));
    const int hx    = swz & 16;

    const char* lb = (const char*)lds;
    f32x4 acc[2] = { cvp[0], cvp[1] };
    #pragma unroll
    for (int kk = 0; kk < 4; ++kk) {
        const float4 f0 = *reinterpret_cast<const float4*>(lb + rbase + kk * 128 + hx);
        const float4 f1 = *reinterpret_cast<const float4*>(lb + rbase + kk * 128 + (16 ^ hx));
        short8 v;
        v[0] = f2bf(f0.x); v[1] = f2bf(f0.y); v[2] = f2bf(f0.z); v[3] = f2bf(f0.w);
        v[4] = f2bf(f1.x); v[5] = f2bf(f1.y); v[6] = f2bf(f1.z); v[7] = f2bf(f1.w);
        acc[0] = __builtin_amdgcn_mfma_f32_16x16x32_bf16(Mfrag[0][kk], v, acc[0], 0, 0, 0);
        acc[1] = __builtin_amdgcn_mfma_f32_16x16x32_bf16(Mfrag[1][kk], v, acc[1], 0, 0, 0);
    }

    // acc[nt] = out[t*16+c][ncol0 + nt*16 + q*4 .. +3]  — contiguous.
    const int orow = t * 16 + c;
    if (orow < E) {
        float* op = out + (size_t)orow * HID + ncol0 + q * 4;
        *reinterpret_cast<f32x4*>(op)      = acc[0];
        *reinterpret_cast<f32x4*>(op + 16) = acc[1];
    }
}

// ---------------------------------------------------------------------------
// Inputs (setup_inputs order, all float32; edge_index int64 — DEAD):
//  0 edge_attr  1 node_features(DEAD)  2 regime_probs(DEAD)
//  3 Wq 4 bq 5 Wk 6 bk (DEAD: softmax over singleton seq = 1 => att = v2)
//  7 Wv 8 bv  9 W_in[3*128,128] 10 b_in[384] (only value third live)
// 11 W_mo 12 b_mo 13 Wo 14 bo 15 edge_index(DEAD)
// out = ea @ (I + 0.5*Wo@W_mo@Wiv@Wv)^T + 0.5*c
// ---------------------------------------------------------------------------
extern "C" void kernel_launch(void* const* d_in, const int* in_sizes, int n_in,
                              void* d_out, int out_size, void* d_ws, size_t ws_size,
                              hipStream_t stream) {
    const float* Wv   = (const float*)d_in[7];
    const float* bv   = (const float*)d_in[8];
    const float* W_in = (const float*)d_in[9];
    const float* b_in = (const float*)d_in[10];
    const float* W_mo = (const float*)d_in[11];
    const float* b_mo = (const float*)d_in[12];
    const float* Wo   = (const float*)d_in[13];
    const float* bo   = (const float*)d_in[14];
    const float* Wiv  = W_in + 2 * HID * HID;   // value third of packed in-proj
    const float* biv  = b_in + 2 * HID;

    char* ws = (char*)d_ws;
    float*          Pl = (float*)(ws);                    // 64 KB
    float*          Pr = (float*)(ws + 65536);            // 64 KB
    __hip_bfloat16* Mb = (__hip_bfloat16*)(ws + 131072);  // 32 KB
    float*          cv = (float*)(ws + 163840);           // 512 B

    const int E = in_sizes[0] / HID;
    const int numTiles = (E + 15) / 16;

    prep_products<<<dim3(257), dim3(HID), 0, stream>>>(
        Wo, W_mo, Wiv, Wv, bv, biv, b_mo, bo, Pl, Pr, cv);
    prep_final<<<dim3(HID), dim3(HID), 0, stream>>>(Pl, Pr, Mb);

    edge_gemm<<<dim3(numTiles), dim3(256), 0, stream>>>(
        (const float*)d_in[0], Mb, cv, (float*)d_out, E, numTiles);
}

// Round 9
// 282.254 us; speedup vs baseline: 1.0864x; 1.0864x over previous
//
#include <hip/hip_runtime.h>
#include <hip/hip_bf16.h>

#define HID 128

typedef __attribute__((ext_vector_type(8))) short short8;   // 8 x bf16 (4 VGPRs)
typedef __attribute__((ext_vector_type(4))) float f32x4;    // MFMA C/D

static __device__ __forceinline__ short f2bf(float x) {
    __hip_bfloat16 h = __float2bfloat16(x);   // RNE
    return *reinterpret_cast<short*>(&h);
}

// ---------------------------------------------------------------------------
// K1: the two INDEPENDENT 128x128 products in one launch, plus the bias
// chain parallelized over its 128 outputs.
// ---------------------------------------------------------------------------
__global__ void prep_products(const float* __restrict__ Wo,
                              const float* __restrict__ W_mo,
                              const float* __restrict__ Wiv,
                              const float* __restrict__ Wv,
                              const float* __restrict__ bv,
                              const float* __restrict__ biv,
                              const float* __restrict__ b_mo,
                              const float* __restrict__ bo,
                              float* __restrict__ Pl,
                              float* __restrict__ Pr,
                              float* __restrict__ cv)
{
    const int j = threadIdx.x;
    const int b = blockIdx.x;
    __shared__ float sh[HID];

    if (b < 256) {
        const float* A = (b < 128) ? Wo   : Wiv;
        const float* B = (b < 128) ? W_mo : Wv;
        float*       C = (b < 128) ? Pl   : Pr;
        const int i = b & 127;
        sh[j] = A[i * HID + j];
        __syncthreads();
        float s = 0.f;
        #pragma unroll 16
        for (int k = 0; k < HID; ++k) s += sh[k] * B[k * HID + j];
        C[i * HID + j] = s;
    } else {
        sh[j] = bv[j];
        __syncthreads();
        float t = biv[j];
        #pragma unroll 16
        for (int k = 0; k < HID; ++k) t += Wiv[j * HID + k] * sh[k];
        __syncthreads(); sh[j] = t; __syncthreads();
        t = b_mo[j];
        #pragma unroll 16
        for (int k = 0; k < HID; ++k) t += W_mo[j * HID + k] * sh[k];
        __syncthreads(); sh[j] = t; __syncthreads();
        t = bo[j];
        #pragma unroll 16
        for (int k = 0; k < HID; ++k) t += Wo[j * HID + k] * sh[k];
        cv[j] = 0.5f * t;
    }
}

// ---------------------------------------------------------------------------
// K2: M' = bf16( I + 0.5 * P_left @ P_right )   (row-major [n][k])
// ---------------------------------------------------------------------------
__global__ void prep_final(const float* __restrict__ Pl,
                           const float* __restrict__ Pr,
                           __hip_bfloat16* __restrict__ Mb)
{
    const int i = blockIdx.x, j = threadIdx.x;
    __shared__ float sh[HID];
    sh[j] = Pl[i * HID + j];
    __syncthreads();
    float s = 0.f;
    #pragma unroll 16
    for (int k = 0; k < HID; ++k) s += sh[k] * Pr[k * HID + j];
    Mb[i * HID + j] = __float2bfloat16(((i == j) ? 1.0f : 0.0f) + 0.5f * s);
}

// ---------------------------------------------------------------------------
// Main: out[e][:] = ea[e][:] @ M'^T + cv      (fp32 in/out, bf16 MFMA)
//
// R9 experiment: per-CU read delivery is pinned at ~2.7 B/cy across ALL
// structures (R0-R8): vector-load only, LDS-DMA only, any occupancy, any
// pipeline depth, loop or loop-free — while m13 streaming copy reads at
// 5.1 B/cy and fillBuffer writes at 10.7 (writes are posted, uncapped).
// Theory: a per-CU outstanding-read budget (~40 lines) caps BW at
// lines*64B/latency. The untested axis: the VECTOR path and the LDS-DMA
// path may hold SEPARATE budgets. This kernel issues both concurrently:
//   rows 0-7 of each tile: global_load_lds (1 instr/wave, pre-swizzled src)
//   rows 8-15: float4 vector loads (16 B/thread) -> swizzled ds_write one
//   iteration later (dep distance = 1 iter, compiler-counted vmcnt).
// Skeleton = R5's proven triple-buffer rotation + counted vmcnt (no full
// drains in-loop). LDS image and fragment ds_reads identical to R5/R7.
// Separate budgets -> reads ~2x -> ~50-58 us. Shared -> null -> roofline.
// ---------------------------------------------------------------------------
__global__ __launch_bounds__(256) void edge_gemm(
    const float* __restrict__ ea,
    const __hip_bfloat16* __restrict__ Mb,   // [128][128] bf16: M'[n][k]
    const float* __restrict__ cvec,          // [128] = 0.5*c
    float* __restrict__ out,
    int E, int numTiles)
{
    __shared__ __align__(16) float lds[3][2048];   // 3 x 16 rows x 512 B

    const int lane  = threadIdx.x & 63;
    const int wv    = threadIdx.x >> 6;
    const int q     = lane >> 4;      // 0..3
    const int c     = lane & 15;      // 0..15
    const int ncol0 = wv * 32;        // this wave's 32 output cols

    // A-frag: lane (q,c) holds M'[ncol0 + nt*16 + c][kk*32 + q*8 .. +7]
    short8 Mfrag[2][4];
    #pragma unroll
    for (int nt = 0; nt < 2; ++nt) {
        const __hip_bfloat16* mp = Mb + (size_t)(ncol0 + nt * 16 + c) * HID + q * 8;
        #pragma unroll
        for (int kk = 0; kk < 4; ++kk)
            Mfrag[nt][kk] = *reinterpret_cast<const short8*>(mp + kk * 32);
    }
    f32x4 cvp[2];
    #pragma unroll
    for (int nt = 0; nt < 2; ++nt)
        cvp[nt] = *reinterpret_cast<const f32x4*>(cvec + ncol0 + nt * 16 + q * 4);

    int t = blockIdx.x;
    if (t >= numTiles) return;
    const int G = gridDim.x;

    // DMA half (rows 0-7): wave wv issues ONE instr covering rows 2wv,2wv+1.
    // LDS dest linear [wv*1024, +1024); source pre-swizzled so the LDS image
    // is LDS[r*512 + x] = ea[r][x ^ ((r&7)<<4)]  (proven R3/R5/R6).
    auto dma_half = [&](float* buf, int edge0) {
        const int r = wv * 2 + (lane >> 5);
        const int b = ((lane & 31) * 16) ^ ((r & 7) << 4);
        int grow = edge0 + r; if (grow > E - 1) grow = E - 1;
        const char* src = (const char*)ea + (size_t)grow * 512 + b;
        float* dst = buf + wv * 256;    // wave-uniform LDS base
        __builtin_amdgcn_global_load_lds(
            (const __attribute__((address_space(1))) void*)src,
            (__attribute__((address_space(3))) void*)dst,
            16, 0, 0);
    };

    // Vector half (rows 8-15): 16 B/thread, 256 threads cover 4 KB.
    const int rrow = 8 + (threadIdx.x >> 5);          // 8..15
    const int roff = (threadIdx.x & 31) * 16;         // byte in row
    const int rwad = rrow * 512 + (roff ^ ((rrow & 7) << 4));  // swizzled LDS byte

    auto reg_load = [&](int edge0, float4& rr) {
        int grow = edge0 + rrow; if (grow > E - 1) grow = E - 1;
        rr = *reinterpret_cast<const float4*>((const char*)ea + (size_t)grow * 512 + roff);
    };
    auto reg_write = [&](float* buf, const float4& rr) {
        *reinterpret_cast<float4*>((char*)buf + rwad) = rr;
    };

    // Fragment ds_read addressing (proven): ea[row c][byte kk*128+q*32+h*16]
    // at LDS byte c*512 + ((kk*128+q*32+h*16) ^ ((c&7)<<4)).
    const int swz   = (c & 7) << 4;
    const int rbase = c * 512 + ((q * 32) ^ (swz & 0x60));
    const int hx    = swz & 16;

    auto compute_store = [&](const float* buf, int tt) {
        const char* lb = (const char*)buf;
        f32x4 acc[2] = { cvp[0], cvp[1] };
        #pragma unroll
        for (int kk = 0; kk < 4; ++kk) {
            const float4 f0 = *reinterpret_cast<const float4*>(lb + rbase + kk * 128 + hx);
            const float4 f1 = *reinterpret_cast<const float4*>(lb + rbase + kk * 128 + (16 ^ hx));
            short8 v;
            v[0] = f2bf(f0.x); v[1] = f2bf(f0.y); v[2] = f2bf(f0.z); v[3] = f2bf(f0.w);
            v[4] = f2bf(f1.x); v[5] = f2bf(f1.y); v[6] = f2bf(f1.z); v[7] = f2bf(f1.w);
            acc[0] = __builtin_amdgcn_mfma_f32_16x16x32_bf16(Mfrag[0][kk], v, acc[0], 0, 0, 0);
            acc[1] = __builtin_amdgcn_mfma_f32_16x16x32_bf16(Mfrag[1][kk], v, acc[1], 0, 0, 0);
        }
        const int orow = tt * 16 + c;
        if (orow < E) {
            float* op = out + (size_t)orow * HID + ncol0 + q * 4;
            *reinterpret_cast<f32x4*>(op)      = acc[0];
            *reinterpret_cast<f32x4*>(op + 16) = acc[1];
        }
    };

    float* br = &lds[0][0];   // holds tile t       (read this iter)
    float* bm = &lds[1][0];   // holds tile t+G
    float* bf = &lds[2][0];   // free (staged with t+2G this iter)
    float4 sA, sB;

    // Prologue: DMA halves of t and t+G; vector halves loaded; tile t's
    // vector half written after a one-time full drain. sB written in iter 0.
    dma_half(br, t * 16);
    reg_load(t * 16, sA);
    const bool h1p = (t + G < numTiles);
    if (h1p) { dma_half(bm, (t + G) * 16); reg_load((t + G) * 16, sB); }
    asm volatile("s_waitcnt vmcnt(0)" ::: "memory");
    reg_write(br, sA);
    asm volatile("s_waitcnt lgkmcnt(0)" ::: "memory");
    __builtin_amdgcn_s_barrier();
    __builtin_amdgcn_sched_barrier(0);

    // Per iteration (tile t): stage t+2G (DMA now into bf; vector load into
    // slot S), ds_write slot So (tile t+G's vector half, loaded last iter)
    // into bm, counted waits, barrier, compute br, rotate. The compiler's
    // dependency vmcnt before the ds_write retires last iter's DMA+load
    // (~1 iter old) while keeping this iter's issues in flight.
    auto body = [&](float4& S, float4& So) -> bool {
        const int t2g = t + 2 * G;
        const bool has1 = (t + G < numTiles);
        const bool has2 = (t2g < numTiles);

        if (has2) { dma_half(bf, t2g * 16); reg_load(t2g * 16, S); }
        if (has1) reg_write(bm, So);

        asm volatile("s_waitcnt vmcnt(7)" ::: "memory");
        asm volatile("s_waitcnt lgkmcnt(0)" ::: "memory");
        __builtin_amdgcn_s_barrier();
        __builtin_amdgcn_sched_barrier(0);

        compute_store(br, t);

        if (!has1) return false;
        float* tmp = br; br = bm; bm = bf; bf = tmp;
        t += G;
        return true;
    };

    while (true) {
        if (!body(sA, sB)) break;   // even phase: load->sA, write sB
        if (!body(sB, sA)) break;   // odd  phase: load->sB, write sA
    }
}

// ---------------------------------------------------------------------------
// Inputs (setup_inputs order, all float32; edge_index int64 — DEAD):
//  0 edge_attr  1 node_features(DEAD)  2 regime_probs(DEAD)
//  3 Wq 4 bq 5 Wk 6 bk (DEAD: softmax over singleton seq = 1 => att = v2)
//  7 Wv 8 bv  9 W_in[3*128,128] 10 b_in[384] (only value third live)
// 11 W_mo 12 b_mo 13 Wo 14 bo 15 edge_index(DEAD)
// out = ea @ (I + 0.5*Wo@W_mo@Wiv@Wv)^T + 0.5*c
// ---------------------------------------------------------------------------
extern "C" void kernel_launch(void* const* d_in, const int* in_sizes, int n_in,
                              void* d_out, int out_size, void* d_ws, size_t ws_size,
                              hipStream_t stream) {
    const float* Wv   = (const float*)d_in[7];
    const float* bv   = (const float*)d_in[8];
    const float* W_in = (const float*)d_in[9];
    const float* b_in = (const float*)d_in[10];
    const float* W_mo = (const float*)d_in[11];
    const float* b_mo = (const float*)d_in[12];
    const float* Wo   = (const float*)d_in[13];
    const float* bo   = (const float*)d_in[14];
    const float* Wiv  = W_in + 2 * HID * HID;   // value third of packed in-proj
    const float* biv  = b_in + 2 * HID;

    char* ws = (char*)d_ws;
    float*          Pl = (float*)(ws);                    // 64 KB
    float*          Pr = (float*)(ws + 65536);            // 64 KB
    __hip_bfloat16* Mb = (__hip_bfloat16*)(ws + 131072);  // 32 KB
    float*          cv = (float*)(ws + 163840);           // 512 B

    const int E = in_sizes[0] / HID;
    const int numTiles = (E + 15) / 16;
    const int grid = numTiles < 2048 ? numTiles : 2048;

    prep_products<<<dim3(257), dim3(HID), 0, stream>>>(
        Wo, W_mo, Wiv, Wv, bv, biv, b_mo, bo, Pl, Pr, cv);
    prep_final<<<dim3(HID), dim3(HID), 0, stream>>>(Pl, Pr, Mb);

    edge_gemm<<<dim3(grid), dim3(256), 0, stream>>>(
        (const float*)d_in[0], Mb, cv, (float*)d_out, E, numTiles);
}

// Round 10
// 279.547 us; speedup vs baseline: 1.0969x; 1.0097x over previous
//
#include <hip/hip_runtime.h>
#include <hip/hip_bf16.h>

#define HID 128

typedef __attribute__((ext_vector_type(8))) short short8;   // 8 x bf16 (4 VGPRs)
typedef __attribute__((ext_vector_type(4))) float f32x4;    // MFMA C/D

static __device__ __forceinline__ short f2bf(float x) {
    __hip_bfloat16 h = __float2bfloat16(x);   // RNE
    return *reinterpret_cast<short*>(&h);
}

// ---------------------------------------------------------------------------
// K1: the two INDEPENDENT 128x128 products in one launch, plus the bias
// chain parallelized over its 128 outputs.
// ---------------------------------------------------------------------------
__global__ void prep_products(const float* __restrict__ Wo,
                              const float* __restrict__ W_mo,
                              const float* __restrict__ Wiv,
                              const float* __restrict__ Wv,
                              const float* __restrict__ bv,
                              const float* __restrict__ biv,
                              const float* __restrict__ b_mo,
                              const float* __restrict__ bo,
                              float* __restrict__ Pl,
                              float* __restrict__ Pr,
                              float* __restrict__ cv)
{
    const int j = threadIdx.x;
    const int b = blockIdx.x;
    __shared__ float sh[HID];

    if (b < 256) {
        const float* A = (b < 128) ? Wo   : Wiv;
        const float* B = (b < 128) ? W_mo : Wv;
        float*       C = (b < 128) ? Pl   : Pr;
        const int i = b & 127;
        sh[j] = A[i * HID + j];
        __syncthreads();
        float s = 0.f;
        #pragma unroll 16
        for (int k = 0; k < HID; ++k) s += sh[k] * B[k * HID + j];
        C[i * HID + j] = s;
    } else {
        sh[j] = bv[j];
        __syncthreads();
        float t = biv[j];
        #pragma unroll 16
        for (int k = 0; k < HID; ++k) t += Wiv[j * HID + k] * sh[k];
        __syncthreads(); sh[j] = t; __syncthreads();
        t = b_mo[j];
        #pragma unroll 16
        for (int k = 0; k < HID; ++k) t += W_mo[j * HID + k] * sh[k];
        __syncthreads(); sh[j] = t; __syncthreads();
        t = bo[j];
        #pragma unroll 16
        for (int k = 0; k < HID; ++k) t += Wo[j * HID + k] * sh[k];
        cv[j] = 0.5f * t;
    }
}

// ---------------------------------------------------------------------------
// K2: M' = bf16( I + 0.5 * P_left @ P_right )   (row-major [n][k])
// ---------------------------------------------------------------------------
__global__ void prep_final(const float* __restrict__ Pl,
                           const float* __restrict__ Pr,
                           __hip_bfloat16* __restrict__ Mb)
{
    const int i = blockIdx.x, j = threadIdx.x;
    __shared__ float sh[HID];
    sh[j] = Pl[i * HID + j];
    __syncthreads();
    float s = 0.f;
    #pragma unroll 16
    for (int k = 0; k < HID; ++k) s += sh[k] * Pr[k * HID + j];
    Mb[i * HID + j] = __float2bfloat16(((i == j) ? 1.0f : 0.0f) + 0.5f * s);
}

// ---------------------------------------------------------------------------
// Main: out[e][:] = ea[e][:] @ M'^T + cv      (fp32 in/out, bf16 MFMA)
//
// R10 experiment: the R0-R9 table collapses onto
//   delivery = resident_waves x ~0.16-0.34 B/cy/wave,
// i.e. each wave round-trips ~one 64B line per ~300-400 cy unless its
// pending queue stays deep continuously (R6's 0.34 = 2x shows headroom).
// The untested variable on the proven 76us R7 skeleton: PER-WAVE PENDING
// DEPTH. Depth 2 lets the queue drain to ~0 every iteration; this kernel
// holds FOUR tiles of loads per thread outstanding at all times (slots
// A-D, statically named; LDS stays 2 x 8KB; the compiler's dependency
// vmcnt before each ds_write waits on a 4-iteration-old load with ~12
// newer VMEM ops still in flight). Single-variable change vs R7.
// ---------------------------------------------------------------------------
__global__ __launch_bounds__(256) void edge_gemm(
    const float* __restrict__ ea,
    const __hip_bfloat16* __restrict__ Mb,   // [128][128] bf16: M'[n][k]
    const float* __restrict__ cvec,          // [128] = 0.5*c
    float* __restrict__ out,
    int E, int numTiles)
{
    __shared__ __align__(16) float lds[2][2048];   // 2 x 16 rows x 512 B

    const int lane  = threadIdx.x & 63;
    const int wv    = threadIdx.x >> 6;
    const int q     = lane >> 4;      // 0..3
    const int c     = lane & 15;      // 0..15
    const int ncol0 = wv * 32;        // this wave's 32 output cols

    // A-frag: lane (q,c) holds M'[ncol0 + nt*16 + c][kk*32 + q*8 .. +7]
    short8 Mfrag[2][4];
    #pragma unroll
    for (int nt = 0; nt < 2; ++nt) {
        const __hip_bfloat16* mp = Mb + (size_t)(ncol0 + nt * 16 + c) * HID + q * 8;
        #pragma unroll
        for (int kk = 0; kk < 4; ++kk)
            Mfrag[nt][kk] = *reinterpret_cast<const short8*>(mp + kk * 32);
    }
    f32x4 cvp[2];
    #pragma unroll
    for (int nt = 0; nt < 2; ++nt)
        cvp[nt] = *reinterpret_cast<const f32x4*>(cvec + ncol0 + nt * 16 + q * 4);

    int t = blockIdx.x;
    if (t >= numTiles) return;
    const int G = gridDim.x;

    // Dense-load addressing: thread tid covers tile bytes [tid*32, +32) =
    // row tid>>4, row-bytes (tid&15)*32 .. +32.  Perfectly coalesced.
    const int ldrow = threadIdx.x >> 4;         // 0..15
    const int ldoff = (threadIdx.x & 15) * 32;  // 32B-aligned byte in row
    // ds_write: global (r, b) lands at LDS byte r*512 + (b ^ ((r&7)<<4)).
    const int wsw  = (ldrow & 7) << 4;
    const int wad0 = ldrow * 512 + (ldoff ^ wsw);
    const int wad1 = wad0 ^ 16;

    // ds_read fragment addressing (proven R3..R9):
    // ea[row c][byte kk*128 + q*32 + h*16] at LDS byte
    // c*512 + ((kk*128 + q*32 + h*16) ^ ((c&7)<<4)); XOR fields disjoint.
    const int swz   = (c & 7) << 4;
    const int rbase = c * 512 + ((q * 32) ^ (swz & 0x60));
    const int hx    = swz & 16;

    auto load_tile = [&](int tt, float4& r0, float4& r1) {
        int row = tt * 16 + ldrow; if (row > E - 1) row = E - 1;
        const char* p = (const char*)ea + (size_t)row * 512 + ldoff;
        r0 = *reinterpret_cast<const float4*>(p);
        r1 = *reinterpret_cast<const float4*>(p + 16);
    };
    auto write_tile = [&](int buf, const float4& r0, const float4& r1) {
        char* lb = (char*)&lds[buf][0];
        *reinterpret_cast<float4*>(lb + wad0) = r0;
        *reinterpret_cast<float4*>(lb + wad1) = r1;
    };
    // lgkmcnt(0): my ds_writes done; barrier. NO vmcnt drain: the 3 newer
    // tiles' loads (12 B/thread-slots) stay in flight across the barrier.
    auto sync = [&]() {
        __builtin_amdgcn_sched_barrier(0);
        asm volatile("s_waitcnt lgkmcnt(0)" ::: "memory");
        __builtin_amdgcn_s_barrier();
        __builtin_amdgcn_sched_barrier(0);
    };
    auto compute_store = [&](int buf, int tt) {
        const char* lb = (const char*)&lds[buf][0];
        f32x4 acc[2] = { cvp[0], cvp[1] };
        #pragma unroll
        for (int kk = 0; kk < 4; ++kk) {
            const float4 f0 = *reinterpret_cast<const float4*>(lb + rbase + kk * 128 + hx);
            const float4 f1 = *reinterpret_cast<const float4*>(lb + rbase + kk * 128 + (16 ^ hx));
            short8 v;
            v[0] = f2bf(f0.x); v[1] = f2bf(f0.y); v[2] = f2bf(f0.z); v[3] = f2bf(f0.w);
            v[4] = f2bf(f1.x); v[5] = f2bf(f1.y); v[6] = f2bf(f1.z); v[7] = f2bf(f1.w);
            acc[0] = __builtin_amdgcn_mfma_f32_16x16x32_bf16(Mfrag[0][kk], v, acc[0], 0, 0, 0);
            acc[1] = __builtin_amdgcn_mfma_f32_16x16x32_bf16(Mfrag[1][kk], v, acc[1], 0, 0, 0);
        }
        const int orow = tt * 16 + c;
        if (orow < E) {
            float* op = out + (size_t)orow * HID + ncol0 + q * 4;
            *reinterpret_cast<f32x4*>(op)      = acc[0];
            *reinterpret_cast<f32x4*>(op + 16) = acc[1];
        }
    };

    // 4-deep register prefetch, statically-named slots A..D (rule #20).
    // Slot for iteration j holds tile t_j; its load was issued at j-4.
    // Buffers alternate 0,1 per iteration (reuse distance 2, one barrier
    // between compute(buf) and the next write(buf) — proven safe in R7).
    float4 a0, a1, b0, b1, c0, c1, d0, d1;
    load_tile(t, a0, a1);
    if (t + 1 * G < numTiles) load_tile(t + 1 * G, b0, b1);
    if (t + 2 * G < numTiles) load_tile(t + 2 * G, c0, c1);
    if (t + 3 * G < numTiles) load_tile(t + 3 * G, d0, d1);

    // ITER(slot, buf): write slot's tile to buf (auto-vmcnt waits only the
    // 4-iter-old load), refill slot with t+4G, sync, compute, advance.
    #define ITER(S0, S1, BUF)                                   \
        {                                                       \
            write_tile(BUF, S0, S1);                            \
            if (t + 4 * G < numTiles) load_tile(t + 4 * G, S0, S1); \
            sync();                                             \
            compute_store(BUF, t);                              \
            if (t + G >= numTiles) return;                      \
            t += G;                                             \
        }

    while (true) {
        ITER(a0, a1, 0)
        ITER(b0, b1, 1)
        ITER(c0, c1, 0)
        ITER(d0, d1, 1)
    }
    #undef ITER
}

// ---------------------------------------------------------------------------
// Inputs (setup_inputs order, all float32; edge_index int64 — DEAD):
//  0 edge_attr  1 node_features(DEAD)  2 regime_probs(DEAD)
//  3 Wq 4 bq 5 Wk 6 bk (DEAD: softmax over singleton seq = 1 => att = v2)
//  7 Wv 8 bv  9 W_in[3*128,128] 10 b_in[384] (only value third live)
// 11 W_mo 12 b_mo 13 Wo 14 bo 15 edge_index(DEAD)
// out = ea @ (I + 0.5*Wo@W_mo@Wiv@Wv)^T + 0.5*c
// ---------------------------------------------------------------------------
extern "C" void kernel_launch(void* const* d_in, const int* in_sizes, int n_in,
                              void* d_out, int out_size, void* d_ws, size_t ws_size,
                              hipStream_t stream) {
    const float* Wv   = (const float*)d_in[7];
    const float* bv   = (const float*)d_in[8];
    const float* W_in = (const float*)d_in[9];
    const float* b_in = (const float*)d_in[10];
    const float* W_mo = (const float*)d_in[11];
    const float* b_mo = (const float*)d_in[12];
    const float* Wo   = (const float*)d_in[13];
    const float* bo   = (const float*)d_in[14];
    const float* Wiv  = W_in + 2 * HID * HID;   // value third of packed in-proj
    const float* biv  = b_in + 2 * HID;

    char* ws = (char*)d_ws;
    float*          Pl = (float*)(ws);                    // 64 KB
    float*          Pr = (float*)(ws + 65536);            // 64 KB
    __hip_bfloat16* Mb = (__hip_bfloat16*)(ws + 131072);  // 32 KB
    float*          cv = (float*)(ws + 163840);           // 512 B

    const int E = in_sizes[0] / HID;
    const int numTiles = (E + 15) / 16;
    const int grid = numTiles < 2048 ? numTiles : 2048;

    prep_products<<<dim3(257), dim3(HID), 0, stream>>>(
        Wo, W_mo, Wiv, Wv, bv, biv, b_mo, bo, Pl, Pr, cv);
    prep_final<<<dim3(HID), dim3(HID), 0, stream>>>(Pl, Pr, Mb);

    edge_gemm<<<dim3(grid), dim3(256), 0, stream>>>(
        (const float*)d_in[0], Mb, cv, (float*)d_out, E, numTiles);
}